// Round 2
// baseline (127.052 us; speedup 1.0000x reference)
//
#include <hip/hip_runtime.h>

#define N_NODES 8192
#define NODE_DIM 128
#define HIDDEN_DIM 256
#define WORDS_PER_ROW 256   // 8192 bits / 32
#define CAP 4096            // max neighbors held in LDS (Poisson(16); P(>CAP) ~ 0)

// ---------------------------------------------------------------------------
// Kernel 1: dedupe edges into a dense N*N bitmask, count distinct out-degree.
// A[src, tgt] = 1 with set semantics -> atomicOr; exactly one thread sees the
// bit transition 0->1 and increments deg[src].
// edge_index arrives as int32 (JAX x64-disabled downcasts int64 -> int32).
// ---------------------------------------------------------------------------
__global__ void dedupe_kernel(const int* __restrict__ e,
                              unsigned int* __restrict__ bitmask,
                              unsigned int* __restrict__ deg, int E) {
    int idx = blockIdx.x * blockDim.x + threadIdx.x;
    if (idx >= E) return;
    int s = e[idx];        // row (src)
    int t = e[E + idx];    // col (tgt)
    unsigned int w = (unsigned int)s * WORDS_PER_ROW + ((unsigned int)t >> 5);
    unsigned int m = 1u << (t & 31);
    unsigned int old = atomicOr(&bitmask[w], m);
    if (!(old & m)) atomicAdd(&deg[s], 1u);
}

// ---------------------------------------------------------------------------
// Kernel 2: per-row gather.  y[i] = Dinv[i]*(sum_j Dinv[j]*x[j] + Dinv[i]*x[i])
// where Dinv[i] = rsqrt(deg[i] + 1).  A self-edge j==i appears in the neighbor
// list AND the identity term -> coefficient 2*Dinv[i]^2 = A_tilde[i][i]=2. OK.
// One block of 128 threads per row: 2 waves scan the 256-word bitmask row into
// an LDS list, then thread d accumulates dimension d across neighbors.
// ---------------------------------------------------------------------------
__global__ __launch_bounds__(128)
void aggregate_kernel(const unsigned int* __restrict__ bitmask,
                      const unsigned int* __restrict__ deg,
                      const float* __restrict__ x,
                      float* __restrict__ y) {
    __shared__ int   cols[CAP];
    __shared__ float djs[CAP];
    __shared__ int   cnt;
    int i = blockIdx.x;
    int d = threadIdx.x;
    if (d == 0) cnt = 0;
    __syncthreads();

    // scan bitmask row -> LDS neighbor list
    for (int w = d; w < WORDS_PER_ROW; w += 128) {
        unsigned int bits = bitmask[i * WORDS_PER_ROW + w];
        while (bits) {
            int b = __builtin_ctz(bits);
            bits &= bits - 1;
            int pos = atomicAdd(&cnt, 1);
            if (pos < CAP) cols[pos] = w * 32 + b;
        }
    }
    __syncthreads();
    int n = cnt < CAP ? cnt : CAP;

    // precompute Dinv[j] for the list
    for (int k = d; k < n; k += 128) {
        djs[k] = rsqrtf((float)deg[cols[k]] + 1.0f);
    }
    __syncthreads();

    float di  = rsqrtf((float)deg[i] + 1.0f);
    float acc = di * x[i * NODE_DIM + d];   // identity term
    for (int k = 0; k < n; ++k) {
        acc += djs[k] * x[cols[k] * NODE_DIM + d];
    }
    y[i * NODE_DIM + d] = di * acc;
}

// ---------------------------------------------------------------------------
// Kernel 3: out[8192,256] = Y[8192,128] @ W[256,128]^T  (fp32 VALU).
// 64x64 tile per 256-thread block; K=128 staged once in LDS *transposed*
// (Yt[k][m], Wt[k][h]) so the inner-loop float4 reads hit consecutive banks
// (conflict-free).  4x4 outputs per thread.
// ---------------------------------------------------------------------------
__global__ __launch_bounds__(256)
void gemm_kernel(const float* __restrict__ Y,
                 const float* __restrict__ W,
                 float* __restrict__ out) {
    __shared__ float Yt[128 * 64];   // [k][m]
    __shared__ float Wt[128 * 64];   // [k][h]
    int tid = threadIdx.x;
    int m0 = blockIdx.y * 64;
    int h0 = blockIdx.x * 64;

    // stage both tiles, transposing on the LDS write (one-time cost)
#pragma unroll
    for (int it = 0; it < 8; ++it) {
        int f  = tid + it * 256;     // float4 index in the 64x128 tile
        int r  = f >> 5;             // tile row 0..63
        int kq = f & 31;             // k-quad 0..31  (k = kq*4)
        float4 v = *(const float4*)&Y[(size_t)(m0 + r) * NODE_DIM + kq * 4];
        Yt[(kq * 4 + 0) * 64 + r] = v.x;
        Yt[(kq * 4 + 1) * 64 + r] = v.y;
        Yt[(kq * 4 + 2) * 64 + r] = v.z;
        Yt[(kq * 4 + 3) * 64 + r] = v.w;
        float4 u = *(const float4*)&W[(size_t)(h0 + r) * NODE_DIM + kq * 4];
        Wt[(kq * 4 + 0) * 64 + r] = u.x;
        Wt[(kq * 4 + 1) * 64 + r] = u.y;
        Wt[(kq * 4 + 2) * 64 + r] = u.z;
        Wt[(kq * 4 + 3) * 64 + r] = u.w;
    }
    __syncthreads();

    int tx = tid & 15;   // -> 4 cols at h0 + tx*4
    int ty = tid >> 4;   // -> 4 rows at m0 + ty*4
    float acc[4][4] = {};
#pragma unroll 4
    for (int k = 0; k < 128; ++k) {
        float4 a = *(const float4*)&Yt[k * 64 + ty * 4];
        float4 b = *(const float4*)&Wt[k * 64 + tx * 4];
        acc[0][0] += a.x * b.x; acc[0][1] += a.x * b.y; acc[0][2] += a.x * b.z; acc[0][3] += a.x * b.w;
        acc[1][0] += a.y * b.x; acc[1][1] += a.y * b.y; acc[1][2] += a.y * b.z; acc[1][3] += a.y * b.w;
        acc[2][0] += a.z * b.x; acc[2][1] += a.z * b.y; acc[2][2] += a.z * b.z; acc[2][3] += a.z * b.w;
        acc[3][0] += a.w * b.x; acc[3][1] += a.w * b.y; acc[3][2] += a.w * b.z; acc[3][3] += a.w * b.w;
    }

#pragma unroll
    for (int i = 0; i < 4; ++i) {
        float4 o;
        o.x = acc[i][0]; o.y = acc[i][1]; o.z = acc[i][2]; o.w = acc[i][3];
        *(float4*)&out[(size_t)(m0 + ty * 4 + i) * HIDDEN_DIM + h0 + tx * 4] = o;
    }
}

extern "C" void kernel_launch(void* const* d_in, const int* in_sizes, int n_in,
                              void* d_out, int out_size, void* d_ws, size_t ws_size,
                              hipStream_t stream) {
    const float* x = (const float*)d_in[0];
    const int*   e = (const int*)d_in[1];   // edge_index delivered as int32 [2, E]
    const float* W = (const float*)d_in[2];
    float*       out = (float*)d_out;
    int E = in_sizes[1] / 2;

    // workspace layout: bitmask (8 MB) | deg (32 KB) | y (4 MB)
    unsigned int* bitmask = (unsigned int*)d_ws;
    unsigned int* deg     = bitmask + (size_t)N_NODES * WORDS_PER_ROW;
    float*        y       = (float*)(deg + N_NODES);

    size_t clear_bytes = ((size_t)N_NODES * WORDS_PER_ROW + N_NODES) * sizeof(unsigned int);
    hipMemsetAsync(d_ws, 0, clear_bytes, stream);

    dedupe_kernel<<<(E + 255) / 256, 256, 0, stream>>>(e, bitmask, deg, E);
    aggregate_kernel<<<N_NODES, 128, 0, stream>>>(bitmask, deg, x, y);
    gemm_kernel<<<dim3(HIDDEN_DIM / 64, N_NODES / 64), 256, 0, stream>>>(y, W, out);
}

// Round 3
// 119.481 us; speedup vs baseline: 1.0634x; 1.0634x over previous
//
#include <hip/hip_runtime.h>

#define N_NODES 8192
#define NODE_DIM 128
#define HIDDEN_DIM 256
#define WORDS_PER_ROW 256   // 8192 bits / 32
#define CAP 96              // max distinct neighbors/row; Poisson(16) -> P(>=96) ~ 1e-40

// ---------------------------------------------------------------------------
// Kernel 1: dedupe edges into a dense N*N bitmask, count distinct out-degree.
// ---------------------------------------------------------------------------
__global__ void dedupe_kernel(const int* __restrict__ e,
                              unsigned int* __restrict__ bitmask,
                              unsigned int* __restrict__ deg, int E) {
    int idx = blockIdx.x * blockDim.x + threadIdx.x;
    if (idx >= E) return;
    int s = e[idx];        // row (src)
    int t = e[E + idx];    // col (tgt)
    unsigned int w = (unsigned int)s * WORDS_PER_ROW + ((unsigned int)t >> 5);
    unsigned int m = 1u << (t & 31);
    unsigned int old = atomicOr(&bitmask[w], m);
    if (!(old & m)) atomicAdd(&deg[s], 1u);
}

// ---------------------------------------------------------------------------
// Kernel 2: z[j][:] = Dinv[j] * x[j][:],  Dinv[j] = rsqrt(deg[j]+1).
// float4-vectorized; removes the dependent deg-gather from the aggregate loop.
// ---------------------------------------------------------------------------
__global__ __launch_bounds__(256)
void scale_kernel(const unsigned int* __restrict__ deg,
                  const float* __restrict__ x,
                  float* __restrict__ z) {
    int q = blockIdx.x * 256 + threadIdx.x;        // float4 index, 262144 total
    int j = q >> 5;                                // 32 float4 per row
    float di = rsqrtf((float)deg[j] + 1.0f);
    float4 v = *(const float4*)&x[(size_t)q * 4];
    v.x *= di; v.y *= di; v.z *= di; v.w *= di;
    *(float4*)&z[(size_t)q * 4] = v;
}

// ---------------------------------------------------------------------------
// Kernel 3: per-row gather-sum.  y[i] = Dinv[i]*(z[i] + sum_j z[cols_j]).
// 256 threads/row: thread w scans bitmask word w (one coalesced 1 KB load),
// then two 128-thread groups accumulate even/odd neighbors (halves the serial
// chain), one LDS exchange combines.  <1 KB LDS -> occupancy not LDS-capped.
// Self-edge: j==i in list + z[i] identity term -> coefficient 2*Dinv[i]^2. OK.
// ---------------------------------------------------------------------------
__global__ __launch_bounds__(256)
void aggregate_kernel(const unsigned int* __restrict__ bitmask,
                      const unsigned int* __restrict__ deg,
                      const float* __restrict__ z,
                      float* __restrict__ y) {
    __shared__ int   cols[CAP];
    __shared__ float part[NODE_DIM];
    __shared__ int   cnt;
    int i   = blockIdx.x;
    int tid = threadIdx.x;
    if (tid == 0) cnt = 0;
    __syncthreads();

    unsigned int bits = bitmask[i * WORDS_PER_ROW + tid];
    while (bits) {
        int b = __builtin_ctz(bits);
        bits &= bits - 1;
        int pos = atomicAdd(&cnt, 1);
        if (pos < CAP) cols[pos] = tid * 32 + b;
    }
    __syncthreads();
    int n = cnt < CAP ? cnt : CAP;

    int g = tid >> 7;          // group 0/1
    int d = tid & 127;         // dim
    float acc = 0.0f;
    for (int k = g; k < n; k += 2) {
        acc += z[(size_t)cols[k] * NODE_DIM + d];
    }
    if (g == 0) part[d] = acc;
    __syncthreads();
    if (g == 1) {
        float di = rsqrtf((float)deg[i] + 1.0f);
        y[(size_t)i * NODE_DIM + d] = di * (z[(size_t)i * NODE_DIM + d] + part[d] + acc);
    }
}

// ---------------------------------------------------------------------------
// Kernel 4: out[8192,256] = Y[8192,128] @ W[256,128]^T  (fp32 VALU).
// 64x64 tile / 256-thread block; K=128 staged transposed in LDS; 4x4 acc.
// ---------------------------------------------------------------------------
__global__ __launch_bounds__(256)
void gemm_kernel(const float* __restrict__ Y,
                 const float* __restrict__ W,
                 float* __restrict__ out) {
    __shared__ float Yt[128 * 64];   // [k][m]
    __shared__ float Wt[128 * 64];   // [k][h]
    int tid = threadIdx.x;
    int m0 = blockIdx.y * 64;
    int h0 = blockIdx.x * 64;

#pragma unroll
    for (int it = 0; it < 8; ++it) {
        int f  = tid + it * 256;
        int r  = f >> 5;
        int kq = f & 31;
        float4 v = *(const float4*)&Y[(size_t)(m0 + r) * NODE_DIM + kq * 4];
        Yt[(kq * 4 + 0) * 64 + r] = v.x;
        Yt[(kq * 4 + 1) * 64 + r] = v.y;
        Yt[(kq * 4 + 2) * 64 + r] = v.z;
        Yt[(kq * 4 + 3) * 64 + r] = v.w;
        float4 u = *(const float4*)&W[(size_t)(h0 + r) * NODE_DIM + kq * 4];
        Wt[(kq * 4 + 0) * 64 + r] = u.x;
        Wt[(kq * 4 + 1) * 64 + r] = u.y;
        Wt[(kq * 4 + 2) * 64 + r] = u.z;
        Wt[(kq * 4 + 3) * 64 + r] = u.w;
    }
    __syncthreads();

    int tx = tid & 15;
    int ty = tid >> 4;
    float acc[4][4] = {};
#pragma unroll 4
    for (int k = 0; k < 128; ++k) {
        float4 a = *(const float4*)&Yt[k * 64 + ty * 4];
        float4 b = *(const float4*)&Wt[k * 64 + tx * 4];
        acc[0][0] += a.x * b.x; acc[0][1] += a.x * b.y; acc[0][2] += a.x * b.z; acc[0][3] += a.x * b.w;
        acc[1][0] += a.y * b.x; acc[1][1] += a.y * b.y; acc[1][2] += a.y * b.z; acc[1][3] += a.y * b.w;
        acc[2][0] += a.z * b.x; acc[2][1] += a.z * b.y; acc[2][2] += a.z * b.z; acc[2][3] += a.z * b.w;
        acc[3][0] += a.w * b.x; acc[3][1] += a.w * b.y; acc[3][2] += a.w * b.z; acc[3][3] += a.w * b.w;
    }

#pragma unroll
    for (int i = 0; i < 4; ++i) {
        float4 o;
        o.x = acc[i][0]; o.y = acc[i][1]; o.z = acc[i][2]; o.w = acc[i][3];
        *(float4*)&out[(size_t)(m0 + ty * 4 + i) * HIDDEN_DIM + h0 + tx * 4] = o;
    }
}

extern "C" void kernel_launch(void* const* d_in, const int* in_sizes, int n_in,
                              void* d_out, int out_size, void* d_ws, size_t ws_size,
                              hipStream_t stream) {
    const float* x = (const float*)d_in[0];
    const int*   e = (const int*)d_in[1];   // edge_index delivered as int32 [2, E]
    const float* W = (const float*)d_in[2];
    float*       out = (float*)d_out;
    int E = in_sizes[1] / 2;

    // workspace layout: bitmask (8 MB) | deg (32 KB) | z (4 MB) | y (4 MB)
    unsigned int* bitmask = (unsigned int*)d_ws;
    unsigned int* deg     = bitmask + (size_t)N_NODES * WORDS_PER_ROW;
    float*        z       = (float*)(deg + N_NODES);
    float*        y       = z + (size_t)N_NODES * NODE_DIM;

    size_t clear_bytes = ((size_t)N_NODES * WORDS_PER_ROW + N_NODES) * sizeof(unsigned int);
    hipMemsetAsync(d_ws, 0, clear_bytes, stream);

    dedupe_kernel<<<(E + 255) / 256, 256, 0, stream>>>(e, bitmask, deg, E);
    scale_kernel<<<(N_NODES * NODE_DIM / 4) / 256, 256, 0, stream>>>(deg, x, z);
    aggregate_kernel<<<N_NODES, 256, 0, stream>>>(bitmask, deg, z, y);
    gemm_kernel<<<dim3(HIDDEN_DIM / 64, N_NODES / 64), 256, 0, stream>>>(y, W, out);
}

// Round 4
// 108.238 us; speedup vs baseline: 1.1738x; 1.1039x over previous
//
#include <hip/hip_runtime.h>

#define N_NODES 8192
#define NODE_DIM 128
#define HIDDEN_DIM 256
#define WORDS_PER_ROW 256   // 8192 bits / 32
#define CAP 96              // max distinct neighbors/row; Poisson(16) -> P(>=96) ~ 1e-40

typedef __attribute__((ext_vector_type(8))) short bf16x8;
typedef __attribute__((ext_vector_type(4))) float f32x4;

static __device__ __forceinline__ unsigned short f2bf(float f) {
    unsigned u = __builtin_bit_cast(unsigned, f);
    unsigned r = u + 0x7fffu + ((u >> 16) & 1u);   // RNE
    return (unsigned short)(r >> 16);
}
static __device__ __forceinline__ float bf2f(unsigned short h) {
    unsigned u = ((unsigned)h) << 16;
    return __builtin_bit_cast(float, u);
}

// ---------------------------------------------------------------------------
// Kernel 1: dedupe edges (set semantics) via N*N bitmask; append each NEW
// target to rowlist[s] at pos = atomicAdd(deg[s]).  deg ends = distinct count.
// ---------------------------------------------------------------------------
__global__ void dedupe_kernel(const int* __restrict__ e,
                              unsigned int* __restrict__ bitmask,
                              unsigned int* __restrict__ deg,
                              int* __restrict__ rowlist, int E) {
    int idx = blockIdx.x * blockDim.x + threadIdx.x;
    if (idx >= E) return;
    int s = e[idx];        // row (src)
    int t = e[E + idx];    // col (tgt)
    unsigned int w = (unsigned int)s * WORDS_PER_ROW + ((unsigned int)t >> 5);
    unsigned int m = 1u << (t & 31);
    unsigned int old = atomicOr(&bitmask[w], m);
    if (!(old & m)) {
        unsigned int p = atomicAdd(&deg[s], 1u);
        if (p < CAP) rowlist[(size_t)s * CAP + p] = t;
    }
}

// ---------------------------------------------------------------------------
// Kernel 2: z[j][:] = Dinv[j]*x[j][:]   (blocks 0..1023)
//           W -> split bf16 (Wh + Wl)   (blocks 1024..1055)
// ---------------------------------------------------------------------------
__global__ __launch_bounds__(256)
void scale_kernel(const unsigned int* __restrict__ deg,
                  const float* __restrict__ x,
                  const float* __restrict__ W,
                  float* __restrict__ z,
                  unsigned short* __restrict__ wh,
                  unsigned short* __restrict__ wl) {
    int b = blockIdx.x;
    if (b < 1024) {
        int q = b * 256 + threadIdx.x;             // float4 index, 262144 total
        int j = q >> 5;                            // 32 float4 per row
        float di = rsqrtf((float)deg[j] + 1.0f);
        float4 v = ((const float4*)x)[q];
        v.x *= di; v.y *= di; v.z *= di; v.w *= di;
        ((float4*)z)[q] = v;
    } else {
        int t = (b - 1024) * 256 + threadIdx.x;    // float4 index into W, 8192 total
        float4 v = ((const float4*)W)[t];
        ushort4 h, l;
        h.x = f2bf(v.x); l.x = f2bf(v.x - bf2f(h.x));
        h.y = f2bf(v.y); l.y = f2bf(v.y - bf2f(h.y));
        h.z = f2bf(v.z); l.z = f2bf(v.z - bf2f(h.z));
        h.w = f2bf(v.w); l.w = f2bf(v.w - bf2f(h.w));
        ((ushort4*)wh)[t] = h;
        ((ushort4*)wl)[t] = l;
    }
}

// ---------------------------------------------------------------------------
// Kernel 3: y[i] = Dinv[i]*(z[i] + sum_j z[cols_j]); emit split-bf16 y.
// No bitmask scan: cols come straight from rowlist (one coalesced load).
// Two 128-thread groups split even/odd neighbors; LDS exchange combines.
// ---------------------------------------------------------------------------
__global__ __launch_bounds__(256)
void aggregate_kernel(const int* __restrict__ rowlist,
                      const unsigned int* __restrict__ deg,
                      const float* __restrict__ z,
                      unsigned short* __restrict__ yh,
                      unsigned short* __restrict__ yl) {
    __shared__ int   cols[CAP];
    __shared__ float part[NODE_DIM];
    int i   = blockIdx.x;
    int tid = threadIdx.x;
    int n   = (int)deg[i];
    if (n > CAP) n = CAP;
    if (tid < n) cols[tid] = rowlist[(size_t)i * CAP + tid];
    __syncthreads();

    int g = tid >> 7;          // group 0/1
    int d = tid & 127;         // dim
    float acc = 0.0f;
    for (int k = g; k < n; k += 2) {
        acc += z[(size_t)cols[k] * NODE_DIM + d];
    }
    if (g == 0) part[d] = acc;
    __syncthreads();
    if (g == 1) {
        float di = rsqrtf((float)n + 1.0f);
        float v  = di * (z[(size_t)i * NODE_DIM + d] + part[d] + acc);
        unsigned short h = f2bf(v);
        unsigned short l = f2bf(v - bf2f(h));
        yh[(size_t)i * NODE_DIM + d] = h;
        yl[(size_t)i * NODE_DIM + d] = l;
    }
}

// ---------------------------------------------------------------------------
// Kernel 4: out[8192,256] = Y[8192,128] @ W[256,128]^T via split-bf16 MFMA:
// out = Yh*Wh + Yh*Wl + Yl*Wh  (fp32-accurate; Yl*Wl term ~1e-5 rel, dropped).
// Block = 64 rows x 64 h; wave w owns 16 h across 4 row-tiles of 16.
// Frags (16x16x32_bf16: A[m=lane&15][k=quad*8+j]) load directly from
// L2-resident bf16 arrays; C/D: col=lane&15, row=quad*4+reg.
// ---------------------------------------------------------------------------
__global__ __launch_bounds__(256)
void gemm_kernel(const unsigned short* __restrict__ Yh,
                 const unsigned short* __restrict__ Yl,
                 const unsigned short* __restrict__ Wh,
                 const unsigned short* __restrict__ Wl,
                 float* __restrict__ out) {
    int tid  = threadIdx.x;
    int wave = tid >> 6;
    int lane = tid & 63;
    int quad = lane >> 4;       // k-quad on inputs, row-quad on output
    int l16  = lane & 15;       // A row within tile / B h within tile / C col
    int m0   = blockIdx.y * 64;
    int hcol = blockIdx.x * 64 + wave * 16 + l16;

    const unsigned short* wh_p = Wh + (size_t)hcol * NODE_DIM + quad * 8;
    const unsigned short* wl_p = Wl + (size_t)hcol * NODE_DIM + quad * 8;
    const unsigned short* yh_p = Yh + (size_t)(m0 + l16) * NODE_DIM + quad * 8;
    const unsigned short* yl_p = Yl + (size_t)(m0 + l16) * NODE_DIM + quad * 8;

    f32x4 acc[4] = {{0,0,0,0},{0,0,0,0},{0,0,0,0},{0,0,0,0}};
#pragma unroll
    for (int ks = 0; ks < 4; ++ks) {
        int k = ks * 32;
        bf16x8 bh = *(const bf16x8*)(wh_p + k);
        bf16x8 bl = *(const bf16x8*)(wl_p + k);
#pragma unroll
        for (int mt = 0; mt < 4; ++mt) {
            bf16x8 ah = *(const bf16x8*)(yh_p + k + mt * 16 * NODE_DIM);
            bf16x8 al = *(const bf16x8*)(yl_p + k + mt * 16 * NODE_DIM);
            acc[mt] = __builtin_amdgcn_mfma_f32_16x16x32_bf16(ah, bh, acc[mt], 0, 0, 0);
            acc[mt] = __builtin_amdgcn_mfma_f32_16x16x32_bf16(ah, bl, acc[mt], 0, 0, 0);
            acc[mt] = __builtin_amdgcn_mfma_f32_16x16x32_bf16(al, bh, acc[mt], 0, 0, 0);
        }
    }

#pragma unroll
    for (int mt = 0; mt < 4; ++mt) {
#pragma unroll
        for (int r = 0; r < 4; ++r) {
            out[(size_t)(m0 + mt * 16 + quad * 4 + r) * HIDDEN_DIM + hcol] = acc[mt][r];
        }
    }
}

extern "C" void kernel_launch(void* const* d_in, const int* in_sizes, int n_in,
                              void* d_out, int out_size, void* d_ws, size_t ws_size,
                              hipStream_t stream) {
    const float* x = (const float*)d_in[0];
    const int*   e = (const int*)d_in[1];   // edge_index delivered as int32 [2, E]
    const float* W = (const float*)d_in[2];
    float*       out = (float*)d_out;
    int E = in_sizes[1] / 2;

    // ws layout: bitmask 8MB | deg 32KB | rowlist 3MB | z 4MB | yh 2MB | yl 2MB | wh 64KB | wl 64KB
    unsigned int*   bitmask = (unsigned int*)d_ws;
    unsigned int*   deg     = bitmask + (size_t)N_NODES * WORDS_PER_ROW;
    int*            rowlist = (int*)(deg + N_NODES);
    float*          z       = (float*)(rowlist + (size_t)N_NODES * CAP);
    unsigned short* yh      = (unsigned short*)(z + (size_t)N_NODES * NODE_DIM);
    unsigned short* yl      = yh + (size_t)N_NODES * NODE_DIM;
    unsigned short* wh      = yl + (size_t)N_NODES * NODE_DIM;
    unsigned short* wl      = wh + (size_t)HIDDEN_DIM * NODE_DIM;

    // zero bitmask + deg (contiguous); rowlist needs no clear (guarded by deg)
    size_t clear_bytes = ((size_t)N_NODES * WORDS_PER_ROW + N_NODES) * sizeof(unsigned int);
    hipMemsetAsync(d_ws, 0, clear_bytes, stream);

    dedupe_kernel<<<(E + 255) / 256, 256, 0, stream>>>(e, bitmask, deg, rowlist, E);
    scale_kernel<<<1024 + 32, 256, 0, stream>>>(deg, x, W, z, wh, wl);
    aggregate_kernel<<<N_NODES, 256, 0, stream>>>(rowlist, deg, z, yh, yl);
    gemm_kernel<<<dim3(HIDDEN_DIM / 64, N_NODES / 64), 256, 0, stream>>>(yh, yl, wh, wl, out);
}

// Round 5
// 104.476 us; speedup vs baseline: 1.2161x; 1.0360x over previous
//
#include <hip/hip_runtime.h>

#define N_NODES 8192
#define NODE_DIM 128
#define HIDDEN_DIM 256
#define WORDS_PER_ROW 256   // 8192 bits / 32
#define CAP 96              // max distinct neighbors/row; Poisson(16) -> P(>=96) ~ 1e-40

typedef __attribute__((ext_vector_type(8))) short bf16x8;
typedef __attribute__((ext_vector_type(4))) float f32x4;

static __device__ __forceinline__ unsigned short f2bf(float f) {
    unsigned u = __builtin_bit_cast(unsigned, f);
    unsigned r = u + 0x7fffu + ((u >> 16) & 1u);   // RNE
    return (unsigned short)(r >> 16);
}
static __device__ __forceinline__ float bf2f(unsigned short h) {
    unsigned u = ((unsigned)h) << 16;
    return __builtin_bit_cast(float, u);
}

// ---------------------------------------------------------------------------
// Kernel 1 (blocks < nEdgeBlocks): dedupe edges (set semantics) via N*N
// bitmask; append each NEW target to rowlist[s]; deg[s] = distinct count.
// Kernel 1 (trailing 32 blocks): W -> split bf16 (Wh + Wl), fused here to
// save a dispatch (independent work, no ordering constraint with edges).
// ---------------------------------------------------------------------------
__global__ void dedupe_kernel(const int* __restrict__ e,
                              unsigned int* __restrict__ bitmask,
                              unsigned int* __restrict__ deg,
                              int* __restrict__ rowlist,
                              const float* __restrict__ W,
                              unsigned short* __restrict__ wh,
                              unsigned short* __restrict__ wl,
                              int E, int nEdgeBlocks) {
    if ((int)blockIdx.x < nEdgeBlocks) {
        int idx = blockIdx.x * 256 + threadIdx.x;
        if (idx >= E) return;
        int s = e[idx];        // row (src)
        int t = e[E + idx];    // col (tgt)
        unsigned int w = (unsigned int)s * WORDS_PER_ROW + ((unsigned int)t >> 5);
        unsigned int m = 1u << (t & 31);
        unsigned int old = atomicOr(&bitmask[w], m);
        if (!(old & m)) {
            unsigned int p = atomicAdd(&deg[s], 1u);
            if (p < CAP) rowlist[(size_t)s * CAP + p] = t;
        }
    } else {
        int t = (blockIdx.x - nEdgeBlocks) * 256 + threadIdx.x;  // float4 idx, 8192 total
        if (t >= HIDDEN_DIM * NODE_DIM / 4) return;
        float4 v = ((const float4*)W)[t];
        ushort4 h, l;
        h.x = f2bf(v.x); l.x = f2bf(v.x - bf2f(h.x));
        h.y = f2bf(v.y); l.y = f2bf(v.y - bf2f(h.y));
        h.z = f2bf(v.z); l.z = f2bf(v.z - bf2f(h.z));
        h.w = f2bf(v.w); l.w = f2bf(v.w - bf2f(h.w));
        ((ushort4*)wh)[t] = h;
        ((ushort4*)wl)[t] = l;
    }
}

// ---------------------------------------------------------------------------
// Kernel 2: y[i] = Dinv[i]*(Dinv[i]*x[i] + sum_j Dinv[j]*x[cols_j]); split-bf16
// output.  Dinv[j] staged per-block in LDS (16 scattered 4B deg loads), so no
// intermediate z array pass is needed.  Two 128-thread groups split even/odd
// neighbors; one LDS exchange combines.
// Self-edge: j==i appears in list with dj==di, plus identity term -> A~[i][i]=2. OK.
// ---------------------------------------------------------------------------
__global__ __launch_bounds__(256)
void aggregate_kernel(const int* __restrict__ rowlist,
                      const unsigned int* __restrict__ deg,
                      const float* __restrict__ x,
                      unsigned short* __restrict__ yh,
                      unsigned short* __restrict__ yl) {
    __shared__ int   cols[CAP];
    __shared__ float djs[CAP];
    __shared__ float part[NODE_DIM];
    int i   = blockIdx.x;
    int tid = threadIdx.x;
    int n   = (int)deg[i];
    if (n > CAP) n = CAP;
    if (tid < n) {
        int c = rowlist[(size_t)i * CAP + tid];
        cols[tid] = c;
        djs[tid]  = rsqrtf((float)deg[c] + 1.0f);
    }
    __syncthreads();

    int g = tid >> 7;          // group 0/1
    int d = tid & 127;         // dim
    float acc = 0.0f;
    for (int k = g; k < n; k += 2) {
        acc += djs[k] * x[(size_t)cols[k] * NODE_DIM + d];
    }
    if (g == 0) part[d] = acc;
    __syncthreads();
    if (g == 1) {
        float di = rsqrtf((float)n + 1.0f);
        float v  = di * (di * x[(size_t)i * NODE_DIM + d] + part[d] + acc);
        unsigned short h = f2bf(v);
        unsigned short l = f2bf(v - bf2f(h));
        yh[(size_t)i * NODE_DIM + d] = h;
        yl[(size_t)i * NODE_DIM + d] = l;
    }
}

// ---------------------------------------------------------------------------
// Kernel 3: out[8192,256] = Y[8192,128] @ W[256,128]^T via split-bf16 MFMA:
// out = Yh*Wh + Yh*Wl + Yl*Wh  (fp32-accurate; Yl*Wl ~1e-5 rel, dropped).
// Block = 64 rows x 64 h; wave w owns 16 h across 4 row-tiles of 16.
// Frags (16x16x32_bf16: A[m=lane&15][k=quad*8+j]) load directly from
// L2-resident bf16 arrays; C/D: col=lane&15, row=quad*4+reg.
// ---------------------------------------------------------------------------
__global__ __launch_bounds__(256)
void gemm_kernel(const unsigned short* __restrict__ Yh,
                 const unsigned short* __restrict__ Yl,
                 const unsigned short* __restrict__ Wh,
                 const unsigned short* __restrict__ Wl,
                 float* __restrict__ out) {
    int tid  = threadIdx.x;
    int wave = tid >> 6;
    int lane = tid & 63;
    int quad = lane >> 4;       // k-quad on inputs, row-quad on output
    int l16  = lane & 15;       // A row within tile / B h within tile / C col
    int m0   = blockIdx.y * 64;
    int hcol = blockIdx.x * 64 + wave * 16 + l16;

    const unsigned short* wh_p = Wh + (size_t)hcol * NODE_DIM + quad * 8;
    const unsigned short* wl_p = Wl + (size_t)hcol * NODE_DIM + quad * 8;
    const unsigned short* yh_p = Yh + (size_t)(m0 + l16) * NODE_DIM + quad * 8;
    const unsigned short* yl_p = Yl + (size_t)(m0 + l16) * NODE_DIM + quad * 8;

    f32x4 acc[4] = {{0,0,0,0},{0,0,0,0},{0,0,0,0},{0,0,0,0}};
#pragma unroll
    for (int ks = 0; ks < 4; ++ks) {
        int k = ks * 32;
        bf16x8 bh = *(const bf16x8*)(wh_p + k);
        bf16x8 bl = *(const bf16x8*)(wl_p + k);
#pragma unroll
        for (int mt = 0; mt < 4; ++mt) {
            bf16x8 ah = *(const bf16x8*)(yh_p + k + mt * 16 * NODE_DIM);
            bf16x8 al = *(const bf16x8*)(yl_p + k + mt * 16 * NODE_DIM);
            acc[mt] = __builtin_amdgcn_mfma_f32_16x16x32_bf16(ah, bh, acc[mt], 0, 0, 0);
            acc[mt] = __builtin_amdgcn_mfma_f32_16x16x32_bf16(ah, bl, acc[mt], 0, 0, 0);
            acc[mt] = __builtin_amdgcn_mfma_f32_16x16x32_bf16(al, bh, acc[mt], 0, 0, 0);
        }
    }

#pragma unroll
    for (int mt = 0; mt < 4; ++mt) {
#pragma unroll
        for (int r = 0; r < 4; ++r) {
            out[(size_t)(m0 + mt * 16 + quad * 4 + r) * HIDDEN_DIM + hcol] = acc[mt][r];
        }
    }
}

extern "C" void kernel_launch(void* const* d_in, const int* in_sizes, int n_in,
                              void* d_out, int out_size, void* d_ws, size_t ws_size,
                              hipStream_t stream) {
    const float* x = (const float*)d_in[0];
    const int*   e = (const int*)d_in[1];   // edge_index delivered as int32 [2, E]
    const float* W = (const float*)d_in[2];
    float*       out = (float*)d_out;
    int E = in_sizes[1] / 2;

    // ws layout: bitmask 8MB | deg 32KB | rowlist 3MB | yh 2MB | yl 2MB | wh 64KB | wl 64KB
    unsigned int*   bitmask = (unsigned int*)d_ws;
    unsigned int*   deg     = bitmask + (size_t)N_NODES * WORDS_PER_ROW;
    int*            rowlist = (int*)(deg + N_NODES);
    unsigned short* yh      = (unsigned short*)(rowlist + (size_t)N_NODES * CAP);
    unsigned short* yl      = yh + (size_t)N_NODES * NODE_DIM;
    unsigned short* wh      = yl + (size_t)N_NODES * NODE_DIM;
    unsigned short* wl      = wh + (size_t)HIDDEN_DIM * NODE_DIM;

    // zero bitmask + deg (contiguous); rowlist needs no clear (guarded by deg)
    size_t clear_bytes = ((size_t)N_NODES * WORDS_PER_ROW + N_NODES) * sizeof(unsigned int);
    hipMemsetAsync(d_ws, 0, clear_bytes, stream);

    int nEdgeBlocks = (E + 255) / 256;
    int nWBlocks    = (HIDDEN_DIM * NODE_DIM / 4 + 255) / 256;   // 32
    dedupe_kernel<<<nEdgeBlocks + nWBlocks, 256, 0, stream>>>(e, bitmask, deg, rowlist,
                                                              W, wh, wl, E, nEdgeBlocks);
    aggregate_kernel<<<N_NODES, 256, 0, stream>>>(rowlist, deg, x, yh, yl);
    gemm_kernel<<<dim3(HIDDEN_DIM / 64, N_NODES / 64), 256, 0, stream>>>(yh, yl, wh, wl, out);
}